// Round 5
// baseline (570.998 us; speedup 1.0000x reference)
//
#include <hip/hip_runtime.h>

// ---------------------------------------------------------------------------
// GNNQNetwork hetero-GAT, MI355X fp32. Round 5.
//
// Random-line-touch minimization (measured ceiling ~1.7 TB/s for gathers):
//  - DRec{ld f16, batch u16, denom f32} 8B: passA gather + atomic hit ONE line
//    (was 3 distinct random lines/edge: LS, LD, DR2).
//  - LS in f16 (2.4 MB; per-et slice <=0.6 MB -> L2-hit).
//  - passA/passB process edge PAIRS (int2/half2 coalesced, 2x gather MLP).
//  - precompute parallelized (24 blocks), reduceP two-stage (208+26 blocks).
// ---------------------------------------------------------------------------

constexpr int kNT = 100000, kNRV = 200000, kNR = 300000, kE = 400000;
constexpr int kEh   = kE / 2;       // 200,000 edge pairs per et
constexpr int kTOTE = 6 * kE;       // 2,400,000 edges
constexpr int kSLOT = 1088;         // per-et P tile: 16x64 acc + 64 cnt
constexpr int kPSZ  = 6 * kSLOT;    // 6528
constexpr int kNB   = 256;          // passB blocks per edge type

struct alignas(8) DRec { _Float16 ld; unsigned short batch; float denom; };

typedef _Float16 h2v __attribute__((ext_vector_type(2)));

// workspace offsets in 4-byte units (total 34.30 MB <= proven 34.61 MB)
constexpr long long OFF_C    = 0;        // 6*2176: C rows + cb@2048
constexpr long long OFF_VS   = 13056;    // 6*20
constexpr long long OFF_VD   = 13176;    // 6*20
constexpr long long OFF_P    = 13296;    // 6528
constexpr long long OFF_P8   = 19824;    // 8*6528
constexpr long long OFF_XCAT = 72048;    // 64*512
constexpr long long OFF_LS16 = 104816;   // 1.2M halves (600000 floats)
constexpr long long OFF_W16  = 704816;   // 2.4M halves (1.2M floats)
constexpr long long OFF_DREC = 1904816;  // 1.2M DRec (8B) = 2.4M floats
constexpr long long OFF_XR   = 4304816;  // 5.2M halves (2.6M floats)
constexpr long long OFF_PB   = 6904816;  // 6*256*1088 = 1,671,168 floats
// end 8,575,984 floats

// per-et tables. src type: rv,t,r,rv,t,r ; dst type: t,rv,rv,r,r,t
__constant__ const int kLSB[6]  = {0, 200000, 300000, 600000, 800000, 900000};
__constant__ const int kDRB[6]  = {0, 100000, 300000, 500000, 800000, 1100000};
__constant__ const int kDLEN[6] = {100000, 200000, 200000, 300000, 300000, 100000};

// ---------------------------------------------------------------------------
// blockIdx.x = et*4 + jc; jc covers 32 columns of C. vs/vd via u=W@a_s, wv=W@a_d.
__global__ __launch_bounds__(256) void precompute_kernel(
    const float* encW_t, const float* encb_t,
    const float* encW_rv, const float* encb_rv,
    const float* encW_r, const float* encb_r,
    const float* W0, const float* as0, const float* ad0,
    const float* W1, const float* as1, const float* ad1,
    const float* W2, const float* as2, const float* ad2,
    const float* W3, const float* as3, const float* ad3,
    const float* W4, const float* as4, const float* ad4,
    const float* W5, const float* as5, const float* ad5,
    float* Cws, float* vsw, float* vdw)
{
  const float* encW[3] = {encW_t, encW_rv, encW_r};
  const float* encb[3] = {encb_t, encb_rv, encb_r};
  const int    Ks[3]   = {8, 13, 4};
  const float* Wv[6]  = {W0, W1, W2, W3, W4, W5};
  const float* asv[6] = {as0, as1, as2, as3, as4, as5};
  const float* adv[6] = {ad0, ad1, ad2, ad3, ad4, ad5};
  const int srcT[6] = {1, 0, 2, 1, 0, 2};
  const int dstT[6] = {0, 1, 1, 2, 2, 0};

  int et = blockIdx.x >> 2;
  int jc = blockIdx.x & 3;
  int tid = threadIdx.x;
  int st = srcT[et], dt = dstT[et];
  const float* eW = encW[st];
  const float* eB = encb[st];
  int K = Ks[st];
  const float* W = Wv[et];

  // C[k][j] = sum_m encW_S[k][m]*W[m][j]; cb[j] = encb_S . W[:,j]
  float* Cslot = Cws + et * 2176;
  for (int idx = tid; idx < (K + 1) * 32; idx += 256) {
    int r = idx >> 5, jj = idx & 31;
    int j = jc * 32 + jj;
    const float* row = (r < K) ? (eW + r * 128) : eB;
    float acc = 0.f;
    for (int m = 0; m < 128; ++m) acc += row[m] * W[m * 128 + j];
    Cslot[(r < K) ? (r * 128 + j) : (2048 + j)] = acc;
  }

  if (jc == 0) {
    __shared__ float us[128], wvs[128];
    const float* a_s = asv[et];
    const float* a_d = adv[et];
    if (tid < 128) {
      float acc = 0.f;
      for (int j = 0; j < 128; ++j) acc += W[tid * 128 + j] * a_s[j];
      us[tid] = acc;
    } else {
      int m = tid - 128;
      float acc = 0.f;
      for (int j = 0; j < 128; ++j) acc += W[m * 128 + j] * a_d[j];
      wvs[m] = acc;
    }
    __syncthreads();
    if (tid <= K) {
      const float* row = (tid < K) ? (eW + tid * 128) : eB;
      float acc = 0.f;
      for (int m = 0; m < 128; ++m) acc += row[m] * us[m];
      vsw[et * 20 + (tid < K ? tid : 16)] = acc;
    }
    int KD = Ks[dt];
    if (tid >= 32 && tid <= 32 + KD) {
      int k = tid - 32;
      const float* row = (k < KD) ? (encW[dt] + k * 128) : encb[dt];
      float acc = 0.f;
      for (int m = 0; m < 128; ++m) acc += row[m] * wvs[m];
      vdw[et * 20 + (k < KD ? k : 16)] = acc;
    }
  }
}

// ---------------------------------------------------------------------------
template <int K, int RH>
__device__ __forceinline__ void prep_one(
    const float* __restrict__ xr, unsigned short b,
    const float* __restrict__ vsA, const float* __restrict__ vsB,
    const float* __restrict__ vdA, const float* __restrict__ vdB,
    _Float16* lsA, _Float16* lsB, DRec* drA, DRec* drB, _Float16* xrec)
{
  float a0 = 0.f, a1 = 0.f, a2 = 0.f, a3 = 0.f;
#pragma unroll
  for (int k = 0; k < K; ++k) {
    float xv = xr[k];
    a0 += xv * vsA[k]; a1 += xv * vsB[k];
    a2 += xv * vdA[k]; a3 += xv * vdB[k];
    xrec[k] = (_Float16)xv;
  }
#pragma unroll
  for (int k = K; k < RH; ++k) xrec[k] = (_Float16)0.f;
  *lsA = (_Float16)(a0 + vsA[16]);
  *lsB = (_Float16)(a1 + vsB[16]);
  DRec rA; rA.ld = (_Float16)(a2 + vdA[16]); rA.batch = b; rA.denom = 0.f;
  DRec rB; rB.ld = (_Float16)(a3 + vdB[16]); rB.batch = b; rB.denom = 0.f;
  *drA = rA;
  *drB = rB;
}

__global__ __launch_bounds__(256) void prep_kernel(
    const float* __restrict__ x_t, const float* __restrict__ x_rv,
    const float* __restrict__ x_r,
    const int* __restrict__ bt, const int* __restrict__ brv,
    const int* __restrict__ br,
    const float* __restrict__ vsw, const float* __restrict__ vdw,
    _Float16* __restrict__ LS16, DRec* __restrict__ DRC,
    _Float16* __restrict__ XR)
{
  int n = blockIdx.x * 256 + threadIdx.x;
  if (n >= kNT + kNRV + kNR) return;
  if (n < kNT) {
    // tile: src roles et1,et4 (K=8); dst roles et0,et5
    prep_one<8, 8>(x_t + n * 8, (unsigned short)bt[n],
                   vsw + 1 * 20, vsw + 4 * 20, vdw + 0 * 20, vdw + 5 * 20,
                   LS16 + 200000 + n, LS16 + 800000 + n,
                   DRC + 0 + n, DRC + 1100000 + n,
                   XR + (long long)n * 8);
  } else if (n < kNT + kNRV) {
    int m = n - kNT;
    // rv: src roles et0,et3 (K=13); dst roles et1,et2
    prep_one<13, 16>(x_rv + m * 13, (unsigned short)brv[m],
                     vsw + 0 * 20, vsw + 3 * 20, vdw + 1 * 20, vdw + 2 * 20,
                     LS16 + 0 + m, LS16 + 600000 + m,
                     DRC + 100000 + m, DRC + 300000 + m,
                     XR + 800000 + (long long)m * 16);
  } else {
    int m = n - kNT - kNRV;
    // road: src roles et2,et5 (K=4); dst roles et3,et4
    prep_one<4, 4>(x_r + m * 4, (unsigned short)br[m],
                   vsw + 2 * 20, vsw + 5 * 20, vdw + 3 * 20, vdw + 4 * 20,
                   LS16 + 300000 + m, LS16 + 900000 + m,
                   DRC + 500000 + m, DRC + 800000 + m,
                   XR + 4000000 + (long long)m * 4);
  }
}

// ---------------------------------------------------------------------------
__global__ __launch_bounds__(256) void passA_kernel(
    const int* s0, const int* s1, const int* s2,
    const int* s3, const int* s4, const int* s5,
    const int* d0, const int* d1, const int* d2,
    const int* d3, const int* d4, const int* d5,
    const _Float16* __restrict__ LS16, DRec* __restrict__ DRC,
    _Float16* __restrict__ W16)
{
  int idx = blockIdx.x * 256 + threadIdx.x;   // pair index
  if (idx >= kTOTE / 2) return;
  int et = idx / kEh;
  int p = idx - et * kEh;
  const int* sp; const int* dp;
  switch (et) {
    case 0: sp = s0; dp = d0; break;
    case 1: sp = s1; dp = d1; break;
    case 2: sp = s2; dp = d2; break;
    case 3: sp = s3; dp = d3; break;
    case 4: sp = s4; dp = d4; break;
    default: sp = s5; dp = d5; break;
  }
  int lsb = kLSB[et], drb = kDRB[et];
  int2 ss = ((const int2*)sp)[p];
  int2 dd = ((const int2*)dp)[p];
  DRec* r0 = &DRC[drb + dd.x];
  DRec* r1 = &DRC[drb + dd.y];
  float t0 = (float)LS16[lsb + ss.x] + (float)r0->ld;
  float t1 = (float)LS16[lsb + ss.y] + (float)r1->ld;
  t0 = t0 > 0.f ? t0 : 0.2f * t0;
  t1 = t1 > 0.f ? t1 : 0.2f * t1;
  _Float16 h0 = (_Float16)__expf(t0);
  _Float16 h1 = (_Float16)__expf(t1);
  h2v hh; hh.x = h0; hh.y = h1;
  ((h2v*)W16)[idx] = hh;
  unsafeAtomicAdd(&r0->denom, (float)h0);
  unsafeAtomicAdd(&r1->denom, (float)h1);
}

// ---------------------------------------------------------------------------
template <int RH>
__device__ __forceinline__ void loadX(const _Float16* __restrict__ xp, float* xv) {
  if constexpr (RH == 4) {
    union { uint2 u; _Float16 h[4]; } U;
    U.u = *(const uint2*)xp;
#pragma unroll
    for (int k = 0; k < RH; ++k) xv[k] = (float)U.h[k];
  } else if constexpr (RH == 8) {
    union { uint4 u; _Float16 h[8]; } U;
    U.u = *(const uint4*)xp;
#pragma unroll
    for (int k = 0; k < RH; ++k) xv[k] = (float)U.h[k];
  } else {
    union { uint4 u[2]; _Float16 h[16]; } U;
    U.u[0] = *(const uint4*)xp;
    U.u[1] = *(const uint4*)(xp + 8);
#pragma unroll
    for (int k = 0; k < RH; ++k) xv[k] = (float)U.h[k];
  }
}

template <int K, int RH>
__device__ __forceinline__ void passB_loop(
    const int* __restrict__ sp, const int* __restrict__ dp,
    int drb, int dlen, long long xrb,
    const h2v* __restrict__ W2et, const DRec* __restrict__ DRC,
    const _Float16* __restrict__ XR, float* __restrict__ lp,
    int start, int stride)
{
  for (int p = start; p < kEh; p += stride) {
    int2 ss = ((const int2*)sp)[p];
    int2 dd = ((const int2*)dp)[p];
    h2v ww = W2et[p];
    DRec r0 = DRC[drb + dd.x];
    DRec r1 = DRC[drb + dd.y];
    const _Float16* xp0 = XR + xrb + (long long)ss.x * RH;
    const _Float16* xp1 = XR + xrb + (long long)ss.y * RH;
    float xv0[RH], xv1[RH];
    loadX<RH>(xp0, xv0);
    loadX<RH>(xp1, xv1);
    float a0 = (float)ww.x / fmaxf(r0.denom, 1e-16f);
    float a1 = (float)ww.y / fmaxf(r1.denom, 1e-16f);
    int b0 = r0.batch, b1 = r1.batch;
#pragma unroll
    for (int k = 0; k < K; ++k) {
      atomicAdd(lp + k * 64 + b0, a0 * xv0[k]);
      atomicAdd(lp + k * 64 + b1, a1 * xv1[k]);
    }
  }
  // cntE: dst nodes with >=1 edge, per batch
  for (int j = start; j < dlen; j += stride) {
    DRec r = DRC[drb + j];
    if (r.denom > 0.f) atomicAdd(lp + 1024 + r.batch, 1.f);
  }
}

__global__ __launch_bounds__(256) void passB_kernel(
    const int* s0, const int* s1, const int* s2,
    const int* s3, const int* s4, const int* s5,
    const int* d0, const int* d1, const int* d2,
    const int* d3, const int* d4, const int* d5,
    const _Float16* __restrict__ W16, const DRec* __restrict__ DRC,
    const _Float16* __restrict__ XR, float* __restrict__ PB)
{
  __shared__ float lp[kSLOT];
  for (int j = threadIdx.x; j < kSLOT; j += 256) lp[j] = 0.f;
  __syncthreads();
  int et  = blockIdx.x / kNB;
  int blk = blockIdx.x - et * kNB;
  int start = blk * 256 + threadIdx.x;
  int stride = kNB * 256;
  int drb = kDRB[et], dlen = kDLEN[et];
  const h2v* W2et = (const h2v*)(W16 + (long long)et * kE);
  switch (et) {
    case 0: passB_loop<13,16>(s0, d0, drb, dlen, 800000,  W2et, DRC, XR, lp, start, stride); break;
    case 1: passB_loop< 8, 8>(s1, d1, drb, dlen, 0,       W2et, DRC, XR, lp, start, stride); break;
    case 2: passB_loop< 4, 4>(s2, d2, drb, dlen, 4000000, W2et, DRC, XR, lp, start, stride); break;
    case 3: passB_loop<13,16>(s3, d3, drb, dlen, 800000,  W2et, DRC, XR, lp, start, stride); break;
    case 4: passB_loop< 8, 8>(s4, d4, drb, dlen, 0,       W2et, DRC, XR, lp, start, stride); break;
    default: passB_loop<4, 4>(s5, d5, drb, dlen, 4000000, W2et, DRC, XR, lp, start, stride); break;
  }
  __syncthreads();
  float* dst = PB + (long long)blockIdx.x * kSLOT;
  for (int j = threadIdx.x; j < kSLOT; j += 256) dst[j] = lp[j];
}

// ---------------------------------------------------------------------------
// stage 1: 8 chunks x 26 j-blocks; each sums 32 of the 256 per-et PB blocks.
__global__ __launch_bounds__(256) void reduce1_kernel(
    const float* __restrict__ PB, float* __restrict__ P8)
{
  int jb = blockIdx.x % 26;
  int c  = blockIdx.x / 26;
  int j = jb * 256 + threadIdx.x;
  if (j >= kPSZ) return;
  int et = j / kSLOT;
  int jj = j - et * kSLOT;
  const float* base = PB + ((long long)(et * kNB + c * 32)) * kSLOT + jj;
  float s = 0.f;
#pragma unroll 8
  for (int t = 0; t < 32; ++t) s += base[(long long)t * kSLOT];
  P8[c * kPSZ + j] = s;
}

__global__ __launch_bounds__(256) void reduce2_kernel(
    const float* __restrict__ P8, float* __restrict__ P)
{
  int j = blockIdx.x * 256 + threadIdx.x;
  if (j >= kPSZ) return;
  float s = 0.f;
#pragma unroll
  for (int c = 0; c < 8; ++c) s += P8[c * kPSZ + j];
  P[j] = s;
}

// ---------------------------------------------------------------------------
__device__ __forceinline__ int lowb(const int* a, int n, int v) {
  int lo = 0, hi = n;
  while (lo < hi) { int mid = (lo + hi) >> 1; if (a[mid] < v) lo = mid + 1; else hi = mid; }
  return lo;
}

__global__ __launch_bounds__(128) void finalize_kernel(
    const int* __restrict__ bt, const int* __restrict__ brv, const int* __restrict__ br,
    const float* __restrict__ xp,
    const float* __restrict__ fc1W, const float* __restrict__ fc1b,
    const float* __restrict__ fc2W, const float* __restrict__ fc2b,
    const float* __restrict__ b_rv2t, const float* __restrict__ b_r2t,
    const float* __restrict__ b_t2rv, const float* __restrict__ b_r2rv,
    const float* __restrict__ b_rv2r, const float* __restrict__ b_t2r,
    const float* __restrict__ Cws, const float* __restrict__ P,
    float* __restrict__ xcat)
{
  int b = blockIdx.x, tid = threadIdx.x;
  __shared__ float xps[64];
  __shared__ float p1s[128];
  __shared__ int cnts[3];
  if (tid < 64) xps[tid] = xp[b * 64 + tid];
  if (tid < 3) {
    const int* ba = (tid == 0) ? bt : (tid == 1 ? brv : br);
    int N = (tid == 0) ? kNT : (tid == 1 ? kNRV : kNR);
    cnts[tid] = lowb(ba, N, b + 1) - lowb(ba, N, b);
  }
  __syncthreads();
  float a = fc1b[tid];
  for (int k = 0; k < 64; ++k) a += xps[k] * fc1W[k * 128 + tid];
  p1s[tid] = fmaxf(a, 0.f);
  __syncthreads();
  float a2 = fc2b[tid];
  for (int k = 0; k < 128; ++k) a2 += p1s[k] * fc2W[k * 128 + tid];
  xcat[b * 512 + 384 + tid] = fmaxf(a2, 0.f);
  const int etA[3] = {0, 1, 3}, etB[3] = {5, 2, 4};
  const int KAv[3] = {13, 8, 13}, KBv[3] = {4, 4, 8};
  for (int t3 = 0; t3 < 3; ++t3) {
    int eA = etA[t3], eB = etB[t3];
    const float* CA = Cws + eA * 2176;
    const float* CB = Cws + eB * 2176;
    const float* pA = P + eA * kSLOT;   // [k*64 + b] layout
    const float* pB = P + eB * kSLOT;
    float cA = pA[1024 + b];
    float cB = pB[1024 + b];
    float v = cA * CA[2048 + tid] + cB * CB[2048 + tid];
    for (int k = 0; k < KAv[t3]; ++k) v += pA[k * 64 + b] * CA[k * 128 + tid];
    for (int k = 0; k < KBv[t3]; ++k) v += pB[k * 64 + b] * CB[k * 128 + tid];
    float cnt = (float)max(cnts[t3], 1);
    const float* bb1 = (t3 == 0) ? b_rv2t : (t3 == 1 ? b_t2rv : b_rv2r);
    const float* bb2 = (t3 == 0) ? b_r2t  : (t3 == 1 ? b_r2rv : b_t2r);
    xcat[b * 512 + t3 * 128 + tid] = v / cnt + bb1[tid] + bb2[tid];
  }
}

// ---------------------------------------------------------------------------
__global__ __launch_bounds__(256) void out_kernel(
    const float* __restrict__ xcat, const float* __restrict__ outW,
    const float* __restrict__ outb, float* __restrict__ out)
{
  int g = blockIdx.x * 256 + threadIdx.x;   // 64*512
  int r = g >> 9, c = g & 511;
  const float* xr = xcat + r * 512;
  float acc = outb[c];
  for (int k = 0; k < 512; ++k) acc += xr[k] * outW[k * 512 + c];
  out[g] = acc;
}

// ---------------------------------------------------------------------------
extern "C" void kernel_launch(void* const* d_in, const int* in_sizes, int n_in,
                              void* d_out, int out_size, void* d_ws, size_t ws_size,
                              hipStream_t stream) {
  const float* x_tile   = (const float*)d_in[0];
  const float* x_rv     = (const float*)d_in[1];
  const float* x_road   = (const float*)d_in[2];
  const float* x_player = (const float*)d_in[3];
  const float* enc_t_W  = (const float*)d_in[4];
  const float* enc_t_b  = (const float*)d_in[5];
  const float* enc_rv_W = (const float*)d_in[6];
  const float* enc_rv_b = (const float*)d_in[7];
  const float* enc_r_W  = (const float*)d_in[8];
  const float* enc_r_b  = (const float*)d_in[9];
  const float* W[6]; const float* As[6]; const float* Ad[6]; const float* Bb[6];
  for (int et = 0; et < 6; ++et) {
    W[et]  = (const float*)d_in[10 + 4 * et];
    As[et] = (const float*)d_in[11 + 4 * et];
    Ad[et] = (const float*)d_in[12 + 4 * et];
    Bb[et] = (const float*)d_in[13 + 4 * et];
  }
  const float* fc1W = (const float*)d_in[34];
  const float* fc1b = (const float*)d_in[35];
  const float* fc2W = (const float*)d_in[36];
  const float* fc2b = (const float*)d_in[37];
  const float* outW = (const float*)d_in[38];
  const float* outb = (const float*)d_in[39];
  const int* esrc[6]; const int* edst[6];
  for (int et = 0; et < 6; ++et) {
    esrc[et] = (const int*)d_in[40 + 2 * et];
    edst[et] = (const int*)d_in[41 + 2 * et];
  }
  const int* batch_t  = (const int*)d_in[52];
  const int* batch_rv = (const int*)d_in[53];
  const int* batch_r  = (const int*)d_in[54];

  float* wsF = (float*)d_ws;
  float* Cws  = wsF + OFF_C;
  float* vsw  = wsF + OFF_VS;
  float* vdw  = wsF + OFF_VD;
  float* P    = wsF + OFF_P;
  float* P8   = wsF + OFF_P8;
  float* xcat = wsF + OFF_XCAT;
  _Float16* LS16 = (_Float16*)(wsF + OFF_LS16);
  _Float16* W16  = (_Float16*)(wsF + OFF_W16);
  DRec* DRC  = (DRec*)(wsF + OFF_DREC);
  _Float16* XR = (_Float16*)(wsF + OFF_XR);
  float* PB   = wsF + OFF_PB;
  float* out  = (float*)d_out;

  precompute_kernel<<<24, 256, 0, stream>>>(
      enc_t_W, enc_t_b, enc_rv_W, enc_rv_b, enc_r_W, enc_r_b,
      W[0], As[0], Ad[0], W[1], As[1], Ad[1], W[2], As[2], Ad[2],
      W[3], As[3], Ad[3], W[4], As[4], Ad[4], W[5], As[5], Ad[5],
      Cws, vsw, vdw);

  prep_kernel<<<(kNT + kNRV + kNR + 255) / 256, 256, 0, stream>>>(
      x_tile, x_rv, x_road, batch_t, batch_rv, batch_r, vsw, vdw,
      LS16, DRC, XR);

  passA_kernel<<<(kTOTE / 2 + 255) / 256, 256, 0, stream>>>(
      esrc[0], esrc[1], esrc[2], esrc[3], esrc[4], esrc[5],
      edst[0], edst[1], edst[2], edst[3], edst[4], edst[5],
      LS16, DRC, W16);

  passB_kernel<<<6 * kNB, 256, 0, stream>>>(
      esrc[0], esrc[1], esrc[2], esrc[3], esrc[4], esrc[5],
      edst[0], edst[1], edst[2], edst[3], edst[4], edst[5],
      W16, DRC, XR, PB);

  reduce1_kernel<<<26 * 8, 256, 0, stream>>>(PB, P8);
  reduce2_kernel<<<26, 256, 0, stream>>>(P8, P);

  finalize_kernel<<<64, 128, 0, stream>>>(
      batch_t, batch_rv, batch_r, x_player,
      fc1W, fc1b, fc2W, fc2b,
      Bb[0], Bb[5], Bb[1], Bb[2], Bb[3], Bb[4],
      Cws, P, xcat);

  out_kernel<<<128, 256, 0, stream>>>(xcat, outW, outb, out);

  (void)in_sizes; (void)n_in; (void)out_size; (void)ws_size;
}

// Round 6
// 554.077 us; speedup vs baseline: 1.0305x; 1.0305x over previous
//
#include <hip/hip_runtime.h>

// ---------------------------------------------------------------------------
// GNNQNetwork hetero-GAT, MI355X fp32. Round 6.
//
//  - passA: f16 LS/LD gathers (separate, L2-resident) + DEDICATED f32 DN
//    atomic array (gather lines never atomically written -> no invalidation
//    ping-pong; round-5 lesson). Quad (int4) edge processing.
//  - passB: XCD-aware slots (blockIdx%8): each XCD's L2 caches only its
//    edge-type's DN+XR slice. Batch id via binary search in LDS-cached
//    per-type boundary table (sorted batch arrays) -> 4B DN gather only.
//  - 7 kernels: precompute(+BD), prep, passA, passB, reduce1, finalize(+red2), out.
// ---------------------------------------------------------------------------

constexpr int kNT = 100000, kNRV = 200000, kNR = 300000, kE = 400000;
constexpr int kEq   = kE / 4;       // 100,000 quads per et
constexpr int kSLOT = 1088;         // P tile: 16x64 acc + 64 cnt
constexpr int kNBB  = 1024;         // passB blocks (8 slots x 128)

typedef _Float16 h2v __attribute__((ext_vector_type(2)));

// workspace offsets in 4-byte units (total 25.02 MB)
constexpr long long OFF_C    = 0;        // 6*2176: C rows + cb@2048
constexpr long long OFF_VS   = 13056;    // 6*20
constexpr long long OFF_VD   = 13176;    // 6*20
constexpr long long OFF_BD   = 13296;    // 3*72 ints: batch boundaries
constexpr long long OFF_PS   = 13512;    // 8*1088 per-slot reduced tiles
constexpr long long OFF_XCAT = 22216;    // 64*512
constexpr long long OFF_LS16 = 54984;    // 1.2M halves (600000 floats)
constexpr long long OFF_LD16 = 654984;   // 1.2M halves
constexpr long long OFF_PB   = 54984;    // aliases LS16/LD16 after passA: 1024*1088
constexpr long long OFF_W16  = 1254984;  // 2.4M halves
constexpr long long OFF_DN   = 2454984;  // 1.2M f32 denominators (ATOMIC-ONLY)
constexpr long long OFF_XR   = 3654984;  // 5.2M halves
// end 6,254,984 floats

// per-et tables. src type: rv,t,r,rv,t,r ; dst type: t,rv,rv,r,r,t
__constant__ const int kLSB[6]  = {0, 200000, 300000, 600000, 800000, 900000};
__constant__ const int kDRB[6]  = {0, 100000, 300000, 500000, 800000, 1100000};
__constant__ const int kDLEN[6] = {100000, 200000, 200000, 300000, 300000, 100000};
__constant__ const int kDstT[6] = {0, 1, 1, 2, 2, 0};
// passB slots: slot -> et, src filter [lo,hi), do-cnt-tail
__constant__ const int cSlotEt[8]  = {1, 2, 4, 5, 0, 0, 3, 3};
__constant__ const int cSlotLo[8]  = {0, 0, 0, 0, 0, 100000, 0, 100000};
__constant__ const int cSlotHi[8]  = {1 << 30, 1 << 30, 1 << 30, 1 << 30,
                                      100000, 200000, 100000, 200000};
__constant__ const int cSlotCnt[8] = {1, 1, 1, 1, 1, 0, 1, 0};

// ---------------------------------------------------------------------------
__device__ __forceinline__ int lowb(const int* a, int n, int v) {
  int lo = 0, hi = n;
  while (lo < hi) { int mid = (lo + hi) >> 1; if (a[mid] < v) lo = mid + 1; else hi = mid; }
  return lo;
}

// ---------------------------------------------------------------------------
// blocks 0..23: et*4+jc computes 32 C-columns; block 24: BD boundary table.
__global__ __launch_bounds__(256) void precompute_kernel(
    const float* encW_t, const float* encb_t,
    const float* encW_rv, const float* encb_rv,
    const float* encW_r, const float* encb_r,
    const float* W0, const float* as0, const float* ad0,
    const float* W1, const float* as1, const float* ad1,
    const float* W2, const float* as2, const float* ad2,
    const float* W3, const float* as3, const float* ad3,
    const float* W4, const float* as4, const float* ad4,
    const float* W5, const float* as5, const float* ad5,
    const int* bt, const int* brv, const int* br,
    float* Cws, float* vsw, float* vdw, int* BD)
{
  int tid = threadIdx.x;
  if (blockIdx.x == 24) {
    if (tid < 3 * 65) {
      int tt = tid / 65, q = tid - tt * 65;
      const int* ba = (tt == 0) ? bt : (tt == 1 ? brv : br);
      int N = (tt == 0) ? kNT : (tt == 1 ? kNRV : kNR);
      BD[tt * 72 + q] = lowb(ba, N, q);
    }
    return;
  }
  const float* encW[3] = {encW_t, encW_rv, encW_r};
  const float* encb[3] = {encb_t, encb_rv, encb_r};
  const int    Ks[3]   = {8, 13, 4};
  const float* Wv[6]  = {W0, W1, W2, W3, W4, W5};
  const float* asv[6] = {as0, as1, as2, as3, as4, as5};
  const float* adv[6] = {ad0, ad1, ad2, ad3, ad4, ad5};
  const int srcT[6] = {1, 0, 2, 1, 0, 2};
  const int dstT[6] = {0, 1, 1, 2, 2, 0};

  int et = blockIdx.x >> 2;
  int jc = blockIdx.x & 3;
  int st = srcT[et], dt = dstT[et];
  const float* eW = encW[st];
  const float* eB = encb[st];
  int K = Ks[st];
  const float* W = Wv[et];

  float* Cslot = Cws + et * 2176;
  for (int idx = tid; idx < (K + 1) * 32; idx += 256) {
    int r = idx >> 5, jj = idx & 31;
    int j = jc * 32 + jj;
    const float* row = (r < K) ? (eW + r * 128) : eB;
    float acc = 0.f;
    for (int m = 0; m < 128; ++m) acc += row[m] * W[m * 128 + j];
    Cslot[(r < K) ? (r * 128 + j) : (2048 + j)] = acc;
  }

  if (jc == 0) {
    __shared__ float us[128], wvs[128];
    const float* a_s = asv[et];
    const float* a_d = adv[et];
    if (tid < 128) {
      float acc = 0.f;
      for (int j = 0; j < 128; ++j) acc += W[tid * 128 + j] * a_s[j];
      us[tid] = acc;
    } else {
      int m = tid - 128;
      float acc = 0.f;
      for (int j = 0; j < 128; ++j) acc += W[m * 128 + j] * a_d[j];
      wvs[m] = acc;
    }
    __syncthreads();
    if (tid <= K) {
      const float* row = (tid < K) ? (eW + tid * 128) : eB;
      float acc = 0.f;
      for (int m = 0; m < 128; ++m) acc += row[m] * us[m];
      vsw[et * 20 + (tid < K ? tid : 16)] = acc;
    }
    int KD = Ks[dt];
    if (tid >= 32 && tid <= 32 + KD) {
      int k = tid - 32;
      const float* row = (k < KD) ? (encW[dt] + k * 128) : encb[dt];
      float acc = 0.f;
      for (int m = 0; m < 128; ++m) acc += row[m] * wvs[m];
      vdw[et * 20 + (k < KD ? k : 16)] = acc;
    }
  }
}

// ---------------------------------------------------------------------------
template <int K, int RH>
__device__ __forceinline__ void prep_one(
    const float* __restrict__ xr,
    const float* __restrict__ vsA, const float* __restrict__ vsB,
    const float* __restrict__ vdA, const float* __restrict__ vdB,
    _Float16* lsA, _Float16* lsB, _Float16* ldA, _Float16* ldB,
    float* dnA, float* dnB, _Float16* xrec)
{
  float a0 = 0.f, a1 = 0.f, a2 = 0.f, a3 = 0.f;
#pragma unroll
  for (int k = 0; k < K; ++k) {
    float xv = xr[k];
    a0 += xv * vsA[k]; a1 += xv * vsB[k];
    a2 += xv * vdA[k]; a3 += xv * vdB[k];
    xrec[k] = (_Float16)xv;
  }
#pragma unroll
  for (int k = K; k < RH; ++k) xrec[k] = (_Float16)0.f;
  *lsA = (_Float16)(a0 + vsA[16]);
  *lsB = (_Float16)(a1 + vsB[16]);
  *ldA = (_Float16)(a2 + vdA[16]);
  *ldB = (_Float16)(a3 + vdB[16]);
  *dnA = 0.f;
  *dnB = 0.f;
}

__global__ __launch_bounds__(256) void prep_kernel(
    const float* __restrict__ x_t, const float* __restrict__ x_rv,
    const float* __restrict__ x_r,
    const float* __restrict__ vsw, const float* __restrict__ vdw,
    _Float16* __restrict__ LS16, _Float16* __restrict__ LD16,
    float* __restrict__ DN, _Float16* __restrict__ XR)
{
  int n = blockIdx.x * 256 + threadIdx.x;
  if (n >= kNT + kNRV + kNR) return;
  if (n < kNT) {
    // tile: src roles et1,et4 (K=8); dst roles et0,et5
    prep_one<8, 8>(x_t + n * 8,
                   vsw + 1 * 20, vsw + 4 * 20, vdw + 0 * 20, vdw + 5 * 20,
                   LS16 + 200000 + n, LS16 + 800000 + n,
                   LD16 + 0 + n, LD16 + 1100000 + n,
                   DN + 0 + n, DN + 1100000 + n,
                   XR + (long long)n * 8);
  } else if (n < kNT + kNRV) {
    int m = n - kNT;
    // rv: src roles et0,et3 (K=13); dst roles et1,et2
    prep_one<13, 16>(x_rv + m * 13,
                     vsw + 0 * 20, vsw + 3 * 20, vdw + 1 * 20, vdw + 2 * 20,
                     LS16 + 0 + m, LS16 + 600000 + m,
                     LD16 + 100000 + m, LD16 + 300000 + m,
                     DN + 100000 + m, DN + 300000 + m,
                     XR + 800000 + (long long)m * 16);
  } else {
    int m = n - kNT - kNRV;
    // road: src roles et2,et5 (K=4); dst roles et3,et4
    prep_one<4, 4>(x_r + m * 4,
                   vsw + 2 * 20, vsw + 5 * 20, vdw + 3 * 20, vdw + 4 * 20,
                   LS16 + 300000 + m, LS16 + 900000 + m,
                   LD16 + 500000 + m, LD16 + 800000 + m,
                   DN + 500000 + m, DN + 800000 + m,
                   XR + 4000000 + (long long)m * 4);
  }
}

// ---------------------------------------------------------------------------
__global__ __launch_bounds__(256) void passA_kernel(
    const int* s0, const int* s1, const int* s2,
    const int* s3, const int* s4, const int* s5,
    const int* d0, const int* d1, const int* d2,
    const int* d3, const int* d4, const int* d5,
    const _Float16* __restrict__ LS16, const _Float16* __restrict__ LD16,
    float* __restrict__ DN, _Float16* __restrict__ W16)
{
  int idx = blockIdx.x * 256 + threadIdx.x;   // quad index
  if (idx >= 6 * kEq) return;
  int et = idx / kEq;
  int q = idx - et * kEq;
  const int* sp; const int* dp;
  switch (et) {
    case 0: sp = s0; dp = d0; break;
    case 1: sp = s1; dp = d1; break;
    case 2: sp = s2; dp = d2; break;
    case 3: sp = s3; dp = d3; break;
    case 4: sp = s4; dp = d4; break;
    default: sp = s5; dp = d5; break;
  }
  int lsb = kLSB[et], drb = kDRB[et];
  int4 ss = ((const int4*)sp)[q];
  int4 dd = ((const int4*)dp)[q];
  int sa[4] = {ss.x, ss.y, ss.z, ss.w};
  int da[4] = {dd.x, dd.y, dd.z, dd.w};
  union { float2 f; _Float16 h[4]; } WU;
  float wa[4];
#pragma unroll
  for (int i = 0; i < 4; ++i) {
    float t = (float)LS16[lsb + sa[i]] + (float)LD16[drb + da[i]];
    t = t > 0.f ? t : 0.2f * t;
    _Float16 h = (_Float16)__expf(t);
    WU.h[i] = h;
    wa[i] = (float)h;
  }
  ((float2*)(W16 + (long long)et * kE))[q] = WU.f;
#pragma unroll
  for (int i = 0; i < 4; ++i) unsafeAtomicAdd(&DN[drb + da[i]], wa[i]);
}

// ---------------------------------------------------------------------------
template <int RH>
__device__ __forceinline__ void loadX(const _Float16* __restrict__ xp, float* xv) {
  if constexpr (RH == 4) {
    union { uint2 u; _Float16 h[4]; } U;
    U.u = *(const uint2*)xp;
#pragma unroll
    for (int k = 0; k < RH; ++k) xv[k] = (float)U.h[k];
  } else if constexpr (RH == 8) {
    union { uint4 u; _Float16 h[8]; } U;
    U.u = *(const uint4*)xp;
#pragma unroll
    for (int k = 0; k < RH; ++k) xv[k] = (float)U.h[k];
  } else {
    union { uint4 u[2]; _Float16 h[16]; } U;
    U.u[0] = *(const uint4*)xp;
    U.u[1] = *(const uint4*)(xp + 8);
#pragma unroll
    for (int k = 0; k < RH; ++k) xv[k] = (float)U.h[k];
  }
}

template <int K, int RH>
__device__ __forceinline__ void passB_loop(
    const int* __restrict__ sp, const int* __restrict__ dp,
    const _Float16* __restrict__ Wet, const float* __restrict__ DN, int drb,
    const _Float16* __restrict__ XR, long long xrb,
    const int* __restrict__ bd, float* __restrict__ lp,
    int lo, int hi, int start, int stride)
{
  for (int q = start; q < kEq; q += stride) {
    int4 ss = ((const int4*)sp)[q];
    int4 dd = ((const int4*)dp)[q];
    union { float2 f; _Float16 h[4]; } WU;
    WU.f = ((const float2*)Wet)[q];
    int sa[4] = {ss.x, ss.y, ss.z, ss.w};
    int da[4] = {dd.x, dd.y, dd.z, dd.w};
#pragma unroll
    for (int i = 0; i < 4; ++i) {
      int s = sa[i], d = da[i];
      if (s >= lo && s < hi) {
        float dn = DN[drb + d];
        float alpha = (float)WU.h[i] / fmaxf(dn, 1e-16f);
        int b = 0;
#pragma unroll
        for (int stp = 32; stp >= 1; stp >>= 1) {
          int nb = b + stp;
          if (nb <= 63 && bd[nb] <= d) b = nb;
        }
        float xv[RH];
        loadX<RH>(XR + xrb + (long long)s * RH, xv);
#pragma unroll
        for (int k = 0; k < K; ++k) atomicAdd(lp + k * 64 + b, alpha * xv[k]);
      }
    }
  }
}

__global__ __launch_bounds__(256) void passB_kernel(
    const int* s0, const int* s1, const int* s2,
    const int* s3, const int* s4, const int* s5,
    const int* d0, const int* d1, const int* d2,
    const int* d3, const int* d4, const int* d5,
    const _Float16* __restrict__ W16, const float* __restrict__ DN,
    const _Float16* __restrict__ XR, const int* __restrict__ BDg,
    float* __restrict__ PB)
{
  __shared__ float lp[kSLOT];
  __shared__ int bd[65];
  int tid = threadIdx.x;
  for (int j = tid; j < kSLOT; j += 256) lp[j] = 0.f;
  int slot = blockIdx.x & 7;
  int blk = blockIdx.x >> 3;           // 0..127
  int et = cSlotEt[slot];
  if (tid < 65) bd[tid] = BDg[kDstT[et] * 72 + tid];
  __syncthreads();
  int lo = cSlotLo[slot], hi = cSlotHi[slot];
  int start = blk * 256 + tid;
  int stride = 128 * 256;
  int drb = kDRB[et];
  const _Float16* Wet = W16 + (long long)et * kE;
  switch (et) {
    case 0: passB_loop<13, 16>(s0, d0, Wet, DN, drb, XR, 800000,  bd, lp, lo, hi, start, stride); break;
    case 1: passB_loop< 8,  8>(s1, d1, Wet, DN, drb, XR, 0,       bd, lp, lo, hi, start, stride); break;
    case 2: passB_loop< 4,  4>(s2, d2, Wet, DN, drb, XR, 4000000, bd, lp, lo, hi, start, stride); break;
    case 3: passB_loop<13, 16>(s3, d3, Wet, DN, drb, XR, 800000,  bd, lp, lo, hi, start, stride); break;
    case 4: passB_loop< 8,  8>(s4, d4, Wet, DN, drb, XR, 0,       bd, lp, lo, hi, start, stride); break;
    default: passB_loop<4,  4>(s5, d5, Wet, DN, drb, XR, 4000000, bd, lp, lo, hi, start, stride); break;
  }
  // cnt tail: dst nodes with >=1 incoming edge, per batch
  if (cSlotCnt[slot]) {
    int dlen = kDLEN[et];
    for (int j = start; j < dlen; j += stride) {
      if (DN[drb + j] > 0.f) {
        int b = 0;
#pragma unroll
        for (int stp = 32; stp >= 1; stp >>= 1) {
          int nb = b + stp;
          if (nb <= 63 && bd[nb] <= j) b = nb;
        }
        atomicAdd(lp + 1024 + b, 1.f);
      }
    }
  }
  __syncthreads();
  float* dst = PB + (long long)blockIdx.x * kSLOT;
  for (int j = tid; j < kSLOT; j += 256) dst[j] = lp[j];
}

// ---------------------------------------------------------------------------
// PS[slot][j] = sum over the slot's 128 blocks. Grid: 8 slots x 5 j-blocks.
__global__ __launch_bounds__(256) void reduce1_kernel(
    const float* __restrict__ PB, float* __restrict__ PS)
{
  int slot = blockIdx.x / 5;
  int jb = blockIdx.x - slot * 5;
  int j = jb * 256 + threadIdx.x;
  if (j >= kSLOT) return;
  float s = 0.f;
#pragma unroll 8
  for (int blk = 0; blk < 128; ++blk)
    s += PB[(long long)(blk * 8 + slot) * kSLOT + j];
  PS[slot * kSLOT + j] = s;
}

// ---------------------------------------------------------------------------
__global__ __launch_bounds__(128) void finalize_kernel(
    const int* __restrict__ BDg,
    const float* __restrict__ xp,
    const float* __restrict__ fc1W, const float* __restrict__ fc1b,
    const float* __restrict__ fc2W, const float* __restrict__ fc2b,
    const float* __restrict__ b_rv2t, const float* __restrict__ b_r2t,
    const float* __restrict__ b_t2rv, const float* __restrict__ b_r2rv,
    const float* __restrict__ b_rv2r, const float* __restrict__ b_t2r,
    const float* __restrict__ Cws, const float* __restrict__ PS,
    float* __restrict__ xcat)
{
  int b = blockIdx.x, tid = threadIdx.x;
  __shared__ float xps[64];
  __shared__ float p1s[128];
  if (tid < 64) xps[tid] = xp[b * 64 + tid];
  __syncthreads();
  float a = fc1b[tid];
  for (int k = 0; k < 64; ++k) a += xps[k] * fc1W[k * 128 + tid];
  p1s[tid] = fmaxf(a, 0.f);
  __syncthreads();
  float a2 = fc2b[tid];
  for (int k = 0; k < 128; ++k) a2 += p1s[k] * fc2W[k * 128 + tid];
  xcat[b * 512 + 384 + tid] = fmaxf(a2, 0.f);

  const int etA[3] = {0, 1, 3}, etB[3] = {5, 2, 4};
  const int KAv[3] = {13, 8, 13}, KBv[3] = {4, 4, 8};
  const int slotA[6] = {4, 0, 1, 6, 2, 3};
  const int slotB[6] = {5, -1, -1, 7, -1, -1};
  for (int t3 = 0; t3 < 3; ++t3) {
    int eA = etA[t3], eB = etB[t3];
    const float* CA = Cws + eA * 2176;
    const float* CB = Cws + eB * 2176;
    int sA1 = slotA[eA], sA2 = slotB[eA];
    int sB1 = slotA[eB], sB2 = slotB[eB];
    const float* PA1 = PS + sA1 * kSLOT;
    const float* PA2 = (sA2 >= 0) ? (PS + sA2 * kSLOT) : nullptr;
    const float* PB1 = PS + sB1 * kSLOT;
    const float* PB2 = (sB2 >= 0) ? (PS + sB2 * kSLOT) : nullptr;
    float cA = PA1[1024 + b] + (PA2 ? PA2[1024 + b] : 0.f);
    float cB = PB1[1024 + b] + (PB2 ? PB2[1024 + b] : 0.f);
    float v = cA * CA[2048 + tid] + cB * CB[2048 + tid];
    for (int k = 0; k < KAv[t3]; ++k) {
      float pv = PA1[k * 64 + b] + (PA2 ? PA2[k * 64 + b] : 0.f);
      v += pv * CA[k * 128 + tid];
    }
    for (int k = 0; k < KBv[t3]; ++k) {
      float pv = PB1[k * 64 + b] + (PB2 ? PB2[k * 64 + b] : 0.f);
      v += pv * CB[k * 128 + tid];
    }
    int cnt = BDg[t3 * 72 + b + 1] - BDg[t3 * 72 + b];
    float cntf = (float)max(cnt, 1);
    const float* bb1 = (t3 == 0) ? b_rv2t : (t3 == 1 ? b_t2rv : b_rv2r);
    const float* bb2 = (t3 == 0) ? b_r2t  : (t3 == 1 ? b_r2rv : b_t2r);
    xcat[b * 512 + t3 * 128 + tid] = v / cntf + bb1[tid] + bb2[tid];
  }
}

// ---------------------------------------------------------------------------
__global__ __launch_bounds__(256) void out_kernel(
    const float* __restrict__ xcat, const float* __restrict__ outW,
    const float* __restrict__ outb, float* __restrict__ out)
{
  int g = blockIdx.x * 256 + threadIdx.x;   // 64*512
  int r = g >> 9, c = g & 511;
  const float* xr = xcat + r * 512;
  float acc = outb[c];
  for (int k = 0; k < 512; ++k) acc += xr[k] * outW[k * 512 + c];
  out[g] = acc;
}

// ---------------------------------------------------------------------------
extern "C" void kernel_launch(void* const* d_in, const int* in_sizes, int n_in,
                              void* d_out, int out_size, void* d_ws, size_t ws_size,
                              hipStream_t stream) {
  const float* x_tile   = (const float*)d_in[0];
  const float* x_rv     = (const float*)d_in[1];
  const float* x_road   = (const float*)d_in[2];
  const float* x_player = (const float*)d_in[3];
  const float* enc_t_W  = (const float*)d_in[4];
  const float* enc_t_b  = (const float*)d_in[5];
  const float* enc_rv_W = (const float*)d_in[6];
  const float* enc_rv_b = (const float*)d_in[7];
  const float* enc_r_W  = (const float*)d_in[8];
  const float* enc_r_b  = (const float*)d_in[9];
  const float* W[6]; const float* As[6]; const float* Ad[6]; const float* Bb[6];
  for (int et = 0; et < 6; ++et) {
    W[et]  = (const float*)d_in[10 + 4 * et];
    As[et] = (const float*)d_in[11 + 4 * et];
    Ad[et] = (const float*)d_in[12 + 4 * et];
    Bb[et] = (const float*)d_in[13 + 4 * et];
  }
  const float* fc1W = (const float*)d_in[34];
  const float* fc1b = (const float*)d_in[35];
  const float* fc2W = (const float*)d_in[36];
  const float* fc2b = (const float*)d_in[37];
  const float* outW = (const float*)d_in[38];
  const float* outb = (const float*)d_in[39];
  const int* esrc[6]; const int* edst[6];
  for (int et = 0; et < 6; ++et) {
    esrc[et] = (const int*)d_in[40 + 2 * et];
    edst[et] = (const int*)d_in[41 + 2 * et];
  }
  const int* batch_t  = (const int*)d_in[52];
  const int* batch_rv = (const int*)d_in[53];
  const int* batch_r  = (const int*)d_in[54];

  float* wsF = (float*)d_ws;
  float* Cws  = wsF + OFF_C;
  float* vsw  = wsF + OFF_VS;
  float* vdw  = wsF + OFF_VD;
  int*   BD   = (int*)(wsF + OFF_BD);
  float* PS   = wsF + OFF_PS;
  float* xcat = wsF + OFF_XCAT;
  _Float16* LS16 = (_Float16*)(wsF + OFF_LS16);
  _Float16* LD16 = (_Float16*)(wsF + OFF_LD16);
  float* PB   = wsF + OFF_PB;          // aliases LS16/LD16 (dead after passA)
  _Float16* W16 = (_Float16*)(wsF + OFF_W16);
  float* DN   = wsF + OFF_DN;
  _Float16* XR = (_Float16*)(wsF + OFF_XR);
  float* out  = (float*)d_out;

  precompute_kernel<<<25, 256, 0, stream>>>(
      enc_t_W, enc_t_b, enc_rv_W, enc_rv_b, enc_r_W, enc_r_b,
      W[0], As[0], Ad[0], W[1], As[1], Ad[1], W[2], As[2], Ad[2],
      W[3], As[3], Ad[3], W[4], As[4], Ad[4], W[5], As[5], Ad[5],
      batch_t, batch_rv, batch_r,
      Cws, vsw, vdw, BD);

  prep_kernel<<<(kNT + kNRV + kNR + 255) / 256, 256, 0, stream>>>(
      x_tile, x_rv, x_road, vsw, vdw, LS16, LD16, DN, XR);

  passA_kernel<<<(6 * kEq + 255) / 256, 256, 0, stream>>>(
      esrc[0], esrc[1], esrc[2], esrc[3], esrc[4], esrc[5],
      edst[0], edst[1], edst[2], edst[3], edst[4], edst[5],
      LS16, LD16, DN, W16);

  passB_kernel<<<kNBB, 256, 0, stream>>>(
      esrc[0], esrc[1], esrc[2], esrc[3], esrc[4], esrc[5],
      edst[0], edst[1], edst[2], edst[3], edst[4], edst[5],
      W16, DN, XR, BD, PB);

  reduce1_kernel<<<40, 256, 0, stream>>>(PB, PS);

  finalize_kernel<<<64, 128, 0, stream>>>(
      BD, x_player,
      fc1W, fc1b, fc2W, fc2b,
      Bb[0], Bb[5], Bb[1], Bb[2], Bb[3], Bb[4],
      Cws, PS, xcat);

  out_kernel<<<128, 256, 0, stream>>>(xcat, outW, outb, out);

  (void)in_sizes; (void)n_in; (void)out_size; (void)ws_size;
}